// Round 7
// baseline (9046.745 us; speedup 1.0000x reference)
//
#include <hip/hip_runtime.h>

typedef __attribute__((ext_vector_type(8))) short bf16x8;
typedef __attribute__((ext_vector_type(8))) unsigned short u16x8;
typedef __attribute__((ext_vector_type(4))) float f32x4;

__device__ __forceinline__ unsigned short f2bf(float f){
    unsigned int u = __builtin_bit_cast(unsigned int, f);
    u += 0x7fffu + ((u >> 16) & 1u);
    return (unsigned short)(u >> 16);
}
__device__ __forceinline__ float bf2f(unsigned short h){
    unsigned int u = ((unsigned int)h) << 16;
    return __builtin_bit_cast(float, u);
}
__device__ __forceinline__ f32x4 mfma16(bf16x8 a, bf16x8 b, f32x4 c){
    return __builtin_amdgcn_mfma_f32_16x16x32_bf16(a, b, c, 0, 0, 0);
}
// async global->LDS, 16B/lane; LDS dest = wave-uniform base + lane*16 (linear)
__device__ __forceinline__ void gl16(const unsigned short* g, unsigned short* l){
    __builtin_amdgcn_global_load_lds(
        (const __attribute__((address_space(1))) unsigned int*)g,
        (__attribute__((address_space(3))) unsigned int*)l, 16, 0, 0);
}
#define BAR() asm volatile("s_barrier" ::: "memory")

// ---------------- x fp32 -> bf16 ----------------
__global__ __launch_bounds__(256) void cvt_x_kernel(const float* __restrict__ x,
                                                    unsigned short* __restrict__ xb){
    size_t i = ((size_t)blockIdx.x * 256 + threadIdx.x) * 4;
    float4 f = *(const float4*)(x + i);
    ushort4 o;
    o.x = f2bf(f.x); o.y = f2bf(f.y); o.z = f2bf(f.z); o.w = f2bf(f.w);
    *(ushort4*)(xb + i) = o;
}

// ---------------- weight transpose+convert: W fp32 [K][ldn] cols [col0,col0+NC) -> Wt bf16 [NC][K] ----------------
__global__ __launch_bounds__(256) void tr_kernel(const float* __restrict__ W, int ldn, int col0, int K,
                                                 unsigned short* __restrict__ Wt){
    __shared__ unsigned short T[64][66];
    const int t  = threadIdx.x;
    const int k0 = blockIdx.x << 6;
    const int n0 = blockIdx.y << 6;
    #pragma unroll
    for (int i = 0; i < 4; ++i){
        const int idx = i*256 + t;
        const int r   = idx >> 4;
        const int c4  = idx & 15;
        float4 v = *(const float4*)(W + (size_t)(k0 + r)*ldn + col0 + n0 + c4*4);
        T[r][c4*4+0] = f2bf(v.x); T[r][c4*4+1] = f2bf(v.y);
        T[r][c4*4+2] = f2bf(v.z); T[r][c4*4+3] = f2bf(v.w);
    }
    __syncthreads();
    const int n  = t >> 2;
    const int ks = (t & 3) * 16;
    u16x8 o0, o1;
    #pragma unroll
    for (int j = 0; j < 8; ++j){ o0[j] = T[ks+j][n]; o1[j] = T[ks+8+j][n]; }
    unsigned short* dst = Wt + (size_t)(n0 + n)*K + k0 + ks;
    *(u16x8*)dst       = o0;
    *(u16x8*)(dst + 8) = o1;
}

// ---------------- 256x256 8-phase GEMM, read-ahead pipelined ----------------
// 512 threads = 8 waves (2M x 4N); BK=64; LDS 128 KiB dbuf; swizzled reads;
// fragment ds_reads issued ONE QUADRANT AHEAD of their MFMA (counted lgkmcnt by
// compiler) so LDS reads overlap the MFMA cluster of the previous quadrant.
// Staging ledger identical to the verified R5/R6 schedule (vmcnt(4) steady state).
#define RD_A(dst, MH, BASE) do { _Pragma("unroll") for (int m_=0;m_<4;++m_){  \
    const int ro_ = (wm*128 + (MH)*64 + m_*16 + llo)*64;                      \
    dst[m_][0] = *(const bf16x8*)&S[(BASE) + ro_ + rdc0];                     \
    dst[m_][1] = *(const bf16x8*)&S[(BASE) + ro_ + rdc1]; } } while(0)

#define RD_B(dst, NH, BASE) do { _Pragma("unroll") for (int n_=0;n_<2;++n_){  \
    const int ro_ = (wn*64 + (NH)*32 + n_*16 + llo)*64;                       \
    dst[n_][0] = *(const bf16x8*)&S[(BASE) + ro_ + rdc0];                     \
    dst[n_][1] = *(const bf16x8*)&S[(BASE) + ro_ + rdc1]; } } while(0)

#define QUAD(Asrc, Bsrc, AB, ACOL) do {                                       \
    __builtin_amdgcn_s_setprio(1);                                            \
    _Pragma("unroll") for (int m_=0;m_<4;++m_){                               \
      _Pragma("unroll") for (int n_=0;n_<2;++n_){                             \
        f32x4 &a_ = acc[(AB)+m_][(ACOL)+n_];                                  \
        a_ = mfma16(Asrc[m_][0], Bsrc[n_][0], a_);                            \
        a_ = mfma16(Asrc[m_][1], Bsrc[n_][1], a_);                            \
    } }                                                                       \
    __builtin_amdgcn_s_setprio(0);                                            \
} while(0)

// One K-tile: 4 phases. CA/CB = current A/B LDS base, NA/NB = next;
// B0U = Bf(nh0) set in use this kt, B0N = set loaded for kt+1.
#define KT_BODY(KT, CA, CB, NA, NB, B0U, B0N) do {                            \
    /* P0: read Q1 frags; stage A1(kt+1); MFMA Q0 */                          \
    RD_B(B1f, 1, CB);                                                         \
    if ((KT) + 1 < NT) stage(pA1, (KT)+1, (NA)+8192);                         \
    BAR();                                                                    \
    QUAD(A0f, B0U, 0, 0);                                                     \
    BAR();                                                                    \
    /* P1: read Q2 frags; stage B1(kt+1); MFMA Q1 */                          \
    RD_A(A1f, 1, CA);                                                         \
    if ((KT) + 1 < NT) stage(pB1, (KT)+1, (NB)+8192);                         \
    BAR();                                                                    \
    QUAD(A0f, B1f, 0, 2);                                                     \
    BAR();                                                                    \
    /* P2: stage B0(kt+2) into CB (all B reads of CB drained); MFMA Q2 */     \
    if ((KT) + 2 < NT) stage(pB0, (KT)+2, (CB));                              \
    BAR();                                                                    \
    QUAD(A1f, B1f, 4, 2);                                                     \
    BAR();                                                                    \
    /* P3: stage A0(kt+2); vmcnt(4) -> buf(kt+1) complete; read Q0(kt+1); MFMA Q3 */ \
    if ((KT) + 2 < NT){                                                       \
        stage(pA0, (KT)+2, (CA));                                             \
        asm volatile("s_waitcnt vmcnt(4)" ::: "memory");                      \
    } else {                                                                  \
        asm volatile("s_waitcnt vmcnt(0)" ::: "memory");                      \
    }                                                                         \
    BAR();                                                                    \
    if ((KT) + 1 < NT){ RD_A(A0f, 0, NA); RD_B(B0N, 0, NB); }                 \
    QUAD(A1f, B0U, 4, 0);                                                     \
    BAR();                                                                    \
} while(0)

template<int EPI>
__global__ __launch_bounds__(512, 2) void gemm256_kernel(
    const unsigned short* __restrict__ A, int K,
    const unsigned short* __restrict__ Bt, int n_off,
    const float* __restrict__ bq, const float* __restrict__ bk_,
    const float* __restrict__ bv_, const float* __restrict__ bo_,
    unsigned short* __restrict__ q_ws,
    float* __restrict__ k_out, float* __restrict__ v_out,
    unsigned short* __restrict__ v_ws,
    float* __restrict__ outp)
{
    __shared__ unsigned short S[65536];   // [2 buf][A 16384 | B 16384] ushorts = 128 KiB

    const int t    = threadIdx.x;
    const int lane = t & 63;
    const int wid  = t >> 6;
    const int wm   = wid >> 2, wn = wid & 3;
    const int llo  = lane & 15, lhi = lane >> 4;
    const int wslot = wid * 512;                         // 1 KiB per wave within 8 KiB chunk
    // read-side swizzle: col ^= ((row>>1)&1)<<4 | (row&1)<<5 ; row bits 0-1 == llo bits 0-1
    const int rdswz = (((llo >> 1) & 1) << 4) | ((llo & 1) << 5);
    const int rdc0  = (lhi * 8) ^ rdswz;
    const int rdc1  = rdc0 ^ 32;

    // XCD-bijective block swizzle (gridDim.x % 8 == 0 by construction)
    const int nwg = gridDim.x;
    const int qx  = nwg >> 3;
    const int nb  = (blockIdx.x & 7) * qx + (blockIdx.x >> 3);
    const int tm  = nb & 15;
    const int tn  = nb >> 4;
    const int brow  = tm * 256;
    const int nbase = tn * 256;
    const int gcol0 = n_off + nbase;

    // staging source (pre-swizzled global addr; LDS stays linear): row = t>>3
    const int srow = t >> 3;                              // 0..63
    const int scol = ((t & 7) * 8) ^ (((t >> 4) & 1) << 4) ^ (((t >> 3) & 1) << 5);
    const unsigned short* pA0 = A  + (size_t)(brow  + srow)*K + scol;
    const unsigned short* pA1 = pA0 + (size_t)128*K;
    const unsigned short* pB0 = Bt + (size_t)(nbase + srow)*K + scol;
    const unsigned short* pB1 = pB0 + (size_t)128*K;

    auto stage = [&](const unsigned short* gb, int ktt, int ldsoff){
        const unsigned short* g0 = gb + (size_t)ktt * 64;
        gl16(g0,                 &S[ldsoff + wslot]);
        gl16(g0 + (size_t)64*K,  &S[ldsoff + wslot + 4096]);
    };

    const f32x4 zero = {0.f,0.f,0.f,0.f};
    f32x4 acc[8][4];
    #pragma unroll
    for (int i = 0; i < 8; ++i)
        #pragma unroll
        for (int j = 0; j < 4; ++j) acc[i][j] = zero;

    bf16x8 A0f[4][2], A1f[4][2], B1f[2][2], B0a[2][2], B0b[2][2];
    const int NT = K >> 6;   // always even (K = 8192 or 16384)

    // prologue: HT(0,B0), HT(0,A0), HT(0,A1), HT(0,B1), HT(1,B0), HT(1,A0)
    stage(pB0, 0, 16384);
    stage(pA0, 0, 0);
    stage(pA1, 0, 8192);
    stage(pB1, 0, 24576);
    stage(pB0, 1, 32768 + 16384);
    stage(pA0, 1, 32768);
    asm volatile("s_waitcnt vmcnt(4)" ::: "memory");
    BAR();
    // prologue reads: Q0 frags of kt=0
    RD_A(A0f, 0, 0);
    RD_B(B0a, 0, 16384);

    for (int kt = 0; kt < NT; kt += 2){
        KT_BODY(kt,     0,     16384, 32768, 49152, B0a, B0b);
        KT_BODY(kt + 1, 32768, 49152, 0,     16384, B0b, B0a);
    }

    // epilogue: C/D layout col=lane&15, row=(lane>>4)*4+r
    #pragma unroll
    for (int mi = 0; mi < 8; ++mi){
        #pragma unroll
        for (int ni = 0; ni < 4; ++ni){
            const int col = gcol0 + wn*64 + ni*16 + llo;
            int region;
            if (EPI == 1)          region = 3;
            else if (col < 16384)  region = 0;
            else if (col < 18432)  region = 1;
            else                   region = 2;
            float bias;
            if (region == 3)      bias = bo_[col];
            else if (region == 0) bias = bq[col];
            else if (region == 1) bias = bk_[col - 16384];
            else                  bias = bv_[col - 18432];
            const int row0 = brow + wm*128 + mi*16 + lhi*4;
            #pragma unroll
            for (int r = 0; r < 4; ++r){
                const float val = acc[mi][ni][r] + bias;
                const size_t rr = (size_t)(row0 + r);
                if (region == 3){
                    outp[rr * 8192 + col] = val;
                } else if (region == 0){
                    q_ws[rr * 16384 + col] = f2bf(val);
                } else if (region == 1){
                    k_out[rr * 2048 + (col - 16384)] = val;
                } else {
                    v_out[rr * 2048 + (col - 18432)] = val;
                    v_ws[rr * 2048 + (col - 18432)]  = f2bf(val);
                }
            }
        }
    }
}

// ---------------- RoPE (pair i, i+64 per thread; NeoX rotate-halves) ----------------
__global__ __launch_bounds__(256) void rope_q_kernel(unsigned short* __restrict__ q){
    const size_t idx = (size_t)blockIdx.x * 256 + threadIdx.x;
    const int i = (int)(idx & 63);
    const int h = (int)((idx >> 6) & 127);
    const int r = (int)(idx >> 13);
    const int s = r & 2047;
    const float inv = exp2f(-(float)i * 0.20762050593046014f);
    float c, sn;
    sincosf((float)s * inv, &sn, &c);
    unsigned short* p = q + (size_t)r * 16384 + h * 128 + i;
    const float v1 = bf2f(p[0]);
    const float v2 = bf2f(p[64]);
    p[0]  = f2bf(v1 * c - v2 * sn);
    p[64] = f2bf(v2 * c + v1 * sn);
}

__global__ __launch_bounds__(256) void rope_k_kernel(float* __restrict__ kio,
                                                     unsigned short* __restrict__ kws){
    const size_t idx = (size_t)blockIdx.x * 256 + threadIdx.x;
    const int i = (int)(idx & 63);
    const int h = (int)((idx >> 6) & 15);
    const int r = (int)(idx >> 10);
    const int s = r & 2047;
    const float inv = exp2f(-(float)i * 0.20762050593046014f);
    float c, sn;
    sincosf((float)s * inv, &sn, &c);
    float* p = kio + (size_t)r * 2048 + h * 128 + i;
    const float v1 = p[0], v2 = p[64];
    const float o1 = v1 * c - v2 * sn;
    const float o2 = v2 * c + v1 * sn;
    p[0] = o1; p[64] = o2;
    unsigned short* pw = kws + (size_t)r * 2048 + h * 128 + i;
    pw[0]  = f2bf(o1);
    pw[64] = f2bf(o2);
}

// ---------------- block-local GQA attention (ao aliases q: own-rows read-before-write) ----------------
__global__ __launch_bounds__(256) void attn_kernel(
    const unsigned short* __restrict__ q,
    const unsigned short* __restrict__ kbf,
    const unsigned short* __restrict__ vbf,
    unsigned short* __restrict__ ao)
{
    __shared__ unsigned short KV[128][136];
    __shared__ unsigned short Pls[4][16][136];

    const int t    = threadIdx.x;
    const int lane = t & 63;
    const int wid  = t >> 6;
    const int llo  = lane & 15, lhi = lane >> 4;

    const int bid = blockIdx.x;
    const int qh  = bid & 1;
    const int g   = (bid >> 1) & 7;
    const int hkv = (bid >> 4) & 15;
    const int blk = (bid >> 8) & 15;
    const int b   = bid >> 12;

    const int h     = hkv * 8 + g;
    const int sbase = b * 2048 + blk * 128;
    const int qbase = sbase + qh * 64 + wid * 16;

    {
        const int row = t >> 1;
        const int d0  = (t & 1) * 64;
        const unsigned short* src = kbf + (size_t)(sbase + row) * 2048 + hkv * 128 + d0;
        #pragma unroll
        for (int i2 = 0; i2 < 8; ++i2)
            *(int4*)&KV[row][d0 + i2*8] = *(const int4*)(src + i2*8);
    }

    bf16x8 qf[4];
    {
        const unsigned short* qp = q + (size_t)(qbase + llo) * 16384 + h * 128 + lhi * 8;
        #pragma unroll
        for (int kc = 0; kc < 4; ++kc)
            qf[kc] = *(const bf16x8*)(qp + kc * 32);
    }

    __syncthreads();

    const f32x4 zero = {0.f,0.f,0.f,0.f};
    f32x4 sc[8];
    #pragma unroll
    for (int ni = 0; ni < 8; ++ni) sc[ni] = zero;
    #pragma unroll
    for (int kc = 0; kc < 4; ++kc){
        #pragma unroll
        for (int ni = 0; ni < 8; ++ni){
            bf16x8 kf = *(const bf16x8*)&KV[ni*16 + llo][kc*32 + lhi*8];
            sc[ni] = mfma16(qf[kc], kf, sc[ni]);
        }
    }

    const float scale = 0.08838834764831845f;
    #pragma unroll
    for (int r = 0; r < 4; ++r){
        float m = sc[0][r];
        #pragma unroll
        for (int ni = 1; ni < 8; ++ni) m = fmaxf(m, sc[ni][r]);
        #pragma unroll
        for (int off = 1; off < 16; off <<= 1) m = fmaxf(m, __shfl_xor(m, off));
        float sum = 0.f;
        #pragma unroll
        for (int ni = 0; ni < 8; ++ni){
            const float p = __expf((sc[ni][r] - m) * scale);
            sc[ni][r] = p; sum += p;
        }
        #pragma unroll
        for (int off = 1; off < 16; off <<= 1) sum += __shfl_xor(sum, off);
        const float rs = 1.f / sum;
        #pragma unroll
        for (int ni = 0; ni < 8; ++ni) sc[ni][r] *= rs;
    }

    #pragma unroll
    for (int ni = 0; ni < 8; ++ni)
        #pragma unroll
        for (int r = 0; r < 4; ++r)
            Pls[wid][lhi*4 + r][ni*16 + llo] = f2bf(sc[ni][r]);

    __syncthreads();

    {
        const int d  = t & 127;
        const int j0 = (t >> 7) * 64;
        const unsigned short* vs = vbf + (size_t)sbase * 2048 + hkv * 128 + d;
        #pragma unroll
        for (int jj = 0; jj < 64; jj += 8){
            u16x8 pk;
            #pragma unroll
            for (int e = 0; e < 8; ++e)
                pk[e] = vs[(size_t)(j0 + jj + e) * 2048];
            *(u16x8*)&KV[d][j0 + jj] = pk;
        }
    }

    __syncthreads();

    f32x4 oc[8];
    #pragma unroll
    for (int ni = 0; ni < 8; ++ni) oc[ni] = zero;
    #pragma unroll
    for (int kc = 0; kc < 4; ++kc){
        bf16x8 pf = *(const bf16x8*)&Pls[wid][llo][kc*32 + lhi*8];
        #pragma unroll
        for (int ni = 0; ni < 8; ++ni){
            bf16x8 vf = *(const bf16x8*)&KV[ni*16 + llo][kc*32 + lhi*8];
            oc[ni] = mfma16(pf, vf, oc[ni]);
        }
    }

    #pragma unroll
    for (int ni = 0; ni < 8; ++ni){
        #pragma unroll
        for (int r = 0; r < 4; ++r){
            const size_t row = (size_t)(qbase + lhi*4 + r);
            ao[row * 16384 + h*128 + ni*16 + llo] = f2bf(oc[ni][r]);
        }
    }
}

// ---------------- launch ----------------
extern "C" void kernel_launch(void* const* d_in, const int* in_sizes, int n_in,
                              void* d_out, int out_size, void* d_ws, size_t ws_size,
                              hipStream_t stream)
{
    const float* x  = (const float*)d_in[0];
    const float* Wq = (const float*)d_in[1];
    const float* bq = (const float*)d_in[2];
    const float* Wk = (const float*)d_in[3];
    const float* bk = (const float*)d_in[4];
    const float* Wv = (const float*)d_in[5];
    const float* bv = (const float*)d_in[6];
    const float* Wo = (const float*)d_in[7];
    const float* bo = (const float*)d_in[8];

    float* outp  = (float*)d_out;                       // (B,S,E)
    float* k_out = outp + (size_t)33554432;             // (B,S,HKV,D)
    float* v_out = outp + (size_t)41943040;             // (B,S,HKV,D)

    // ws layout (peak 352 MB): [xb 64M][kb2 16M][vb2 16M][qb 128M][Wt 128M]
    char* w = (char*)d_ws;
    unsigned short* xb  = (unsigned short*)(w);
    unsigned short* kb2 = (unsigned short*)(w + 67108864ull);
    unsigned short* vb2 = (unsigned short*)(w + 83886080ull);
    unsigned short* qb  = (unsigned short*)(w + 100663296ull);
    unsigned short* Wt  = (unsigned short*)(w + 234881024ull);

    cvt_x_kernel<<<32768, 256, 0, stream>>>(x, xb);

    // qkv GEMM in 5 column chunks of 4096 (grid 256 = exactly 1 block/CU round)
    for (int c = 0; c < 4; ++c){
        tr_kernel<<<dim3(128, 64), 256, 0, stream>>>(Wq, 16384, c*4096, 8192, Wt);
        gemm256_kernel<0><<<256, 512, 0, stream>>>(xb, 8192, Wt, c*4096, bq, bk, bv, nullptr,
                                                   qb, k_out, v_out, vb2, nullptr);
    }
    // chunk 4 = Wk (2048) + Wv (2048)
    tr_kernel<<<dim3(128, 32), 256, 0, stream>>>(Wk, 2048, 0, 8192, Wt);
    tr_kernel<<<dim3(128, 32), 256, 0, stream>>>(Wv, 2048, 0, 8192, Wt + (size_t)2048*8192);
    gemm256_kernel<0><<<256, 512, 0, stream>>>(xb, 8192, Wt, 16384, bq, bk, bv, nullptr,
                                               qb, k_out, v_out, vb2, nullptr);

    rope_q_kernel<<<131072, 256, 0, stream>>>(qb);
    rope_k_kernel<<<16384, 256, 0, stream>>>(k_out, kb2);
    attn_kernel<<<8192, 256, 0, stream>>>(qb, kb2, vb2, qb);   // ao in-place over q

    // out-proj in 2 column halves of 4096
    for (int hh = 0; hh < 2; ++hh){
        tr_kernel<<<dim3(256, 64), 256, 0, stream>>>(Wo, 8192, hh*4096, 16384, Wt);
        gemm256_kernel<1><<<256, 512, 0, stream>>>(qb, 16384, Wt, hh*4096, nullptr, nullptr, nullptr, bo,
                                                   nullptr, nullptr, nullptr, nullptr, outp);
    }
}

// Round 8
// 2665.528 us; speedup vs baseline: 3.3940x; 3.3940x over previous
//
#include <hip/hip_runtime.h>

typedef __attribute__((ext_vector_type(8))) short bf16x8;
typedef __attribute__((ext_vector_type(8))) unsigned short u16x8;
typedef __attribute__((ext_vector_type(4))) float f32x4;

__device__ __forceinline__ unsigned short f2bf(float f){
    unsigned int u = __builtin_bit_cast(unsigned int, f);
    u += 0x7fffu + ((u >> 16) & 1u);
    return (unsigned short)(u >> 16);
}
__device__ __forceinline__ float bf2f(unsigned short h){
    unsigned int u = ((unsigned int)h) << 16;
    return __builtin_bit_cast(float, u);
}
__device__ __forceinline__ f32x4 mfma16(bf16x8 a, bf16x8 b, f32x4 c){
    return __builtin_amdgcn_mfma_f32_16x16x32_bf16(a, b, c, 0, 0, 0);
}
// async global->LDS, 16B/lane; LDS dest = wave-uniform base + lane*16 (linear)
__device__ __forceinline__ void gl16(const unsigned short* g, unsigned short* l){
    __builtin_amdgcn_global_load_lds(
        (const __attribute__((address_space(1))) unsigned int*)g,
        (__attribute__((address_space(3))) unsigned int*)l, 16, 0, 0);
}
#define BAR() asm volatile("s_barrier" ::: "memory")

// ---------------- x fp32 -> bf16 ----------------
__global__ __launch_bounds__(256) void cvt_x_kernel(const float* __restrict__ x,
                                                    unsigned short* __restrict__ xb){
    size_t i = ((size_t)blockIdx.x * 256 + threadIdx.x) * 4;
    float4 f = *(const float4*)(x + i);
    ushort4 o;
    o.x = f2bf(f.x); o.y = f2bf(f.y); o.z = f2bf(f.z); o.w = f2bf(f.w);
    *(ushort4*)(xb + i) = o;
}

// ---------------- weight transpose+convert: W fp32 [K][ldn] cols [col0,col0+NC) -> Wt bf16 [NC][K] ----------------
__global__ __launch_bounds__(256) void tr_kernel(const float* __restrict__ W, int ldn, int col0, int K,
                                                 unsigned short* __restrict__ Wt){
    __shared__ unsigned short T[64][66];
    const int t  = threadIdx.x;
    const int k0 = blockIdx.x << 6;
    const int n0 = blockIdx.y << 6;
    #pragma unroll
    for (int i = 0; i < 4; ++i){
        const int idx = i*256 + t;
        const int r   = idx >> 4;
        const int c4  = idx & 15;
        float4 v = *(const float4*)(W + (size_t)(k0 + r)*ldn + col0 + n0 + c4*4);
        T[r][c4*4+0] = f2bf(v.x); T[r][c4*4+1] = f2bf(v.y);
        T[r][c4*4+2] = f2bf(v.z); T[r][c4*4+3] = f2bf(v.w);
    }
    __syncthreads();
    const int n  = t >> 2;
    const int ks = (t & 3) * 16;
    u16x8 o0, o1;
    #pragma unroll
    for (int j = 0; j < 8; ++j){ o0[j] = T[ks+j][n]; o1[j] = T[ks+8+j][n]; }
    unsigned short* dst = Wt + (size_t)(n0 + n)*K + k0 + ks;
    *(u16x8*)dst       = o0;
    *(u16x8*)(dst + 8) = o1;
}

// ---------------- 256x256 GEMM, 4 phases/kt, ONE barrier per phase ----------------
// 512 threads = 8 waves (2M x 4N); BK=64; LDS 128 KiB dbuf; swizzled reads;
// counted vmcnt(4); setprio around MFMA. Race ledger: every stage(P) targets a
// region whose reads were issued at phase <= P-2 and drained by lgkmcnt(0)
// before that wave's MFMA(P-2) < every wave's BAR(P-1) < stage(P) issue.
#define READ_A(MH) do { _Pragma("unroll") for (int m_=0;m_<4;++m_){           \
    const int ro_ = (wm*128 + (MH)*64 + m_*16 + llo)*64;                      \
    Af[m_][0] = *(const bf16x8*)&S[curA + ro_ + rdc0];                        \
    Af[m_][1] = *(const bf16x8*)&S[curA + ro_ + rdc1]; } } while(0)

#define READ_B(NH) do { _Pragma("unroll") for (int n_=0;n_<2;++n_){           \
    const int ro_ = (wn*64 + (NH)*32 + n_*16 + llo)*64;                       \
    Bf[(NH)*2+n_][0] = *(const bf16x8*)&S[curB + ro_ + rdc0];                 \
    Bf[(NH)*2+n_][1] = *(const bf16x8*)&S[curB + ro_ + rdc1]; } } while(0)

#define QUADRANT(AB, NH) do {                                                 \
    __builtin_amdgcn_s_setprio(1);                                            \
    _Pragma("unroll") for (int m_=0;m_<4;++m_){                               \
      _Pragma("unroll") for (int n_=0;n_<2;++n_){                             \
        f32x4 &a_ = acc[(AB)+m_][(NH)*2+n_];                                  \
        a_ = mfma16(Af[m_][0], Bf[(NH)*2+n_][0], a_);                         \
        a_ = mfma16(Af[m_][1], Bf[(NH)*2+n_][1], a_);                         \
    } }                                                                       \
    __builtin_amdgcn_s_setprio(0);                                            \
} while(0)

template<int EPI>
__global__ __launch_bounds__(512, 2) void gemm256_kernel(
    const unsigned short* __restrict__ A, int K,
    const unsigned short* __restrict__ Bt, int n_off,
    const float* __restrict__ bq, const float* __restrict__ bk_,
    const float* __restrict__ bv_, const float* __restrict__ bo_,
    unsigned short* __restrict__ q_ws,
    float* __restrict__ k_out, float* __restrict__ v_out,
    unsigned short* __restrict__ v_ws,
    float* __restrict__ outp)
{
    __shared__ unsigned short S[65536];   // [2 buf][A 16384 | B 16384] ushorts = 128 KiB

    const int t    = threadIdx.x;
    const int lane = t & 63;
    const int wid  = t >> 6;
    const int wm   = wid >> 2, wn = wid & 3;
    const int llo  = lane & 15, lhi = lane >> 4;
    const int wslot = wid * 512;                         // 1 KiB per wave within 8 KiB chunk
    // read-side swizzle: col ^= ((row>>1)&1)<<4 | (row&1)<<5 ; row bits 0-1 == llo bits 0-1
    const int rdswz = (((llo >> 1) & 1) << 4) | ((llo & 1) << 5);
    const int rdc0  = (lhi * 8) ^ rdswz;
    const int rdc1  = rdc0 ^ 32;

    // XCD supertile: grid 256 = 16x16 tiles; XCD j owns a 4tm x 8tn region
    // (per-XCD unique bytes/kt 384KB, A slice shared by 8 blocks, B by 4, in-L2)
    const int j  = blockIdx.x & 7;
    const int w  = blockIdx.x >> 3;                      // 0..31
    const int tm = (j & 3) * 4 + (w & 3);
    const int tn = (j >> 2) * 8 + (w >> 2);
    const int brow  = tm * 256;
    const int nbase = tn * 256;
    const int gcol0 = n_off + nbase;

    // staging source (pre-swizzled global addr; LDS stays linear): row = t>>3
    const int srow = t >> 3;                              // 0..63
    const int scol = ((t & 7) * 8) ^ (((t >> 4) & 1) << 4) ^ (((t >> 3) & 1) << 5);
    const unsigned short* pA0 = A  + (size_t)(brow  + srow)*K + scol;
    const unsigned short* pA1 = pA0 + (size_t)128*K;
    const unsigned short* pB0 = Bt + (size_t)(nbase + srow)*K + scol;
    const unsigned short* pB1 = pB0 + (size_t)128*K;

    auto stage = [&](const unsigned short* gb, int ktt, int ldsoff){
        const unsigned short* g0 = gb + (size_t)ktt * 64;
        gl16(g0,                 &S[ldsoff + wslot]);
        gl16(g0 + (size_t)64*K,  &S[ldsoff + wslot + 4096]);
    };

    const f32x4 zero = {0.f,0.f,0.f,0.f};
    f32x4 acc[8][4];
    #pragma unroll
    for (int i = 0; i < 8; ++i)
        #pragma unroll
        for (int jj = 0; jj < 4; ++jj) acc[i][jj] = zero;

    bf16x8 Af[4][2], Bf[4][2];
    const int NT = K >> 6;

    // prologue: HT(0,B0), HT(0,A0), HT(0,A1), HT(0,B1), HT(1,B0), HT(1,A0)
    stage(pB0, 0, 16384);
    stage(pA0, 0, 0);
    stage(pA1, 0, 8192);
    stage(pB1, 0, 24576);
    stage(pB0, 1, 32768 + 16384);
    stage(pA0, 1, 32768);
    asm volatile("s_waitcnt vmcnt(4)" ::: "memory");
    BAR();

    for (int kt = 0; kt < NT; ++kt){
        const int cur = kt & 1, nxt = cur ^ 1;
        const int curA = cur * 32768, curB = curA + 16384;
        const int nxtA = nxt * 32768, nxtB = nxtA + 16384;

        // ---- phase 0: quadrant (mh0, nh0) ----
        READ_A(0); READ_B(0);
        if (kt + 1 < NT) stage(pA1, kt + 1, nxtA + 8192);
        BAR();
        QUADRANT(0, 0);

        // ---- phase 1: quadrant (mh0, nh1) ----
        READ_B(1);
        if (kt + 1 < NT) stage(pB1, kt + 1, nxtB + 8192);
        BAR();
        QUADRANT(0, 1);

        // ---- phase 2: quadrant (mh1, nh1) ----
        READ_A(1);
        if (kt + 2 < NT) stage(pB0, kt + 2, curB);
        BAR();
        QUADRANT(4, 1);

        // ---- phase 3: quadrant (mh1, nh0) ----
        if (kt + 2 < NT){
            stage(pA0, kt + 2, curA);
            asm volatile("s_waitcnt vmcnt(4)" ::: "memory");
        } else {
            asm volatile("s_waitcnt vmcnt(0)" ::: "memory");
        }
        BAR();
        QUADRANT(4, 0);
    }

    // epilogue: C/D layout col=lane&15, row=(lane>>4)*4+r
    #pragma unroll
    for (int mi = 0; mi < 8; ++mi){
        #pragma unroll
        for (int ni = 0; ni < 4; ++ni){
            const int col = gcol0 + wn*64 + ni*16 + llo;
            int region;
            if (EPI == 1)          region = 3;
            else if (col < 16384)  region = 0;
            else if (col < 18432)  region = 1;
            else                   region = 2;
            float bias;
            if (region == 3)      bias = bo_[col];
            else if (region == 0) bias = bq[col];
            else if (region == 1) bias = bk_[col - 16384];
            else                  bias = bv_[col - 18432];
            const int row0 = brow + wm*128 + mi*16 + lhi*4;
            #pragma unroll
            for (int r = 0; r < 4; ++r){
                const float val = acc[mi][ni][r] + bias;
                const size_t rr = (size_t)(row0 + r);
                if (region == 3){
                    outp[rr * 8192 + col] = val;
                } else if (region == 0){
                    q_ws[rr * 16384 + col] = f2bf(val);
                } else if (region == 1){
                    k_out[rr * 2048 + (col - 16384)] = val;
                } else {
                    v_out[rr * 2048 + (col - 18432)] = val;
                    v_ws[rr * 2048 + (col - 18432)]  = f2bf(val);
                }
            }
        }
    }
}

// ---------------- RoPE (pair i, i+64 per thread; NeoX rotate-halves) ----------------
__global__ __launch_bounds__(256) void rope_q_kernel(unsigned short* __restrict__ q){
    const size_t idx = (size_t)blockIdx.x * 256 + threadIdx.x;
    const int i = (int)(idx & 63);
    const int h = (int)((idx >> 6) & 127);
    const int r = (int)(idx >> 13);
    const int s = r & 2047;
    const float inv = exp2f(-(float)i * 0.20762050593046014f);
    float c, sn;
    sincosf((float)s * inv, &sn, &c);
    unsigned short* p = q + (size_t)r * 16384 + h * 128 + i;
    const float v1 = bf2f(p[0]);
    const float v2 = bf2f(p[64]);
    p[0]  = f2bf(v1 * c - v2 * sn);
    p[64] = f2bf(v2 * c + v1 * sn);
}

__global__ __launch_bounds__(256) void rope_k_kernel(float* __restrict__ kio,
                                                     unsigned short* __restrict__ kws){
    const size_t idx = (size_t)blockIdx.x * 256 + threadIdx.x;
    const int i = (int)(idx & 63);
    const int h = (int)((idx >> 6) & 15);
    const int r = (int)(idx >> 10);
    const int s = r & 2047;
    const float inv = exp2f(-(float)i * 0.20762050593046014f);
    float c, sn;
    sincosf((float)s * inv, &sn, &c);
    float* p = kio + (size_t)r * 2048 + h * 128 + i;
    const float v1 = p[0], v2 = p[64];
    const float o1 = v1 * c - v2 * sn;
    const float o2 = v2 * c + v1 * sn;
    p[0] = o1; p[64] = o2;
    unsigned short* pw = kws + (size_t)r * 2048 + h * 128 + i;
    pw[0]  = f2bf(o1);
    pw[64] = f2bf(o2);
}

// ---------------- block-local GQA attention (ao aliases q: own-rows read-before-write) ----------------
__global__ __launch_bounds__(256) void attn_kernel(
    const unsigned short* __restrict__ q,
    const unsigned short* __restrict__ kbf,
    const unsigned short* __restrict__ vbf,
    unsigned short* __restrict__ ao)
{
    __shared__ unsigned short KV[128][136];
    __shared__ unsigned short Pls[4][16][136];

    const int t    = threadIdx.x;
    const int lane = t & 63;
    const int wid  = t >> 6;
    const int llo  = lane & 15, lhi = lane >> 4;

    const int bid = blockIdx.x;
    const int qh  = bid & 1;
    const int g   = (bid >> 1) & 7;
    const int hkv = (bid >> 4) & 15;
    const int blk = (bid >> 8) & 15;
    const int b   = bid >> 12;

    const int h     = hkv * 8 + g;
    const int sbase = b * 2048 + blk * 128;
    const int qbase = sbase + qh * 64 + wid * 16;

    {
        const int row = t >> 1;
        const int d0  = (t & 1) * 64;
        const unsigned short* src = kbf + (size_t)(sbase + row) * 2048 + hkv * 128 + d0;
        #pragma unroll
        for (int i2 = 0; i2 < 8; ++i2)
            *(int4*)&KV[row][d0 + i2*8] = *(const int4*)(src + i2*8);
    }

    bf16x8 qf[4];
    {
        const unsigned short* qp = q + (size_t)(qbase + llo) * 16384 + h * 128 + lhi * 8;
        #pragma unroll
        for (int kc = 0; kc < 4; ++kc)
            qf[kc] = *(const bf16x8*)(qp + kc * 32);
    }

    __syncthreads();

    const f32x4 zero = {0.f,0.f,0.f,0.f};
    f32x4 sc[8];
    #pragma unroll
    for (int ni = 0; ni < 8; ++ni) sc[ni] = zero;
    #pragma unroll
    for (int kc = 0; kc < 4; ++kc){
        #pragma unroll
        for (int ni = 0; ni < 8; ++ni){
            bf16x8 kf = *(const bf16x8*)&KV[ni*16 + llo][kc*32 + lhi*8];
            sc[ni] = mfma16(qf[kc], kf, sc[ni]);
        }
    }

    const float scale = 0.08838834764831845f;
    #pragma unroll
    for (int r = 0; r < 4; ++r){
        float m = sc[0][r];
        #pragma unroll
        for (int ni = 1; ni < 8; ++ni) m = fmaxf(m, sc[ni][r]);
        #pragma unroll
        for (int off = 1; off < 16; off <<= 1) m = fmaxf(m, __shfl_xor(m, off));
        float sum = 0.f;
        #pragma unroll
        for (int ni = 0; ni < 8; ++ni){
            const float p = __expf((sc[ni][r] - m) * scale);
            sc[ni][r] = p; sum += p;
        }
        #pragma unroll
        for (int off = 1; off < 16; off <<= 1) sum += __shfl_xor(sum, off);
        const float rs = 1.f / sum;
        #pragma unroll
        for (int ni = 0; ni < 8; ++ni) sc[ni][r] *= rs;
    }

    #pragma unroll
    for (int ni = 0; ni < 8; ++ni)
        #pragma unroll
        for (int r = 0; r < 4; ++r)
            Pls[wid][lhi*4 + r][ni*16 + llo] = f2bf(sc[ni][r]);

    __syncthreads();

    {
        const int d  = t & 127;
        const int j0 = (t >> 7) * 64;
        const unsigned short* vs = vbf + (size_t)sbase * 2048 + hkv * 128 + d;
        #pragma unroll
        for (int jj = 0; jj < 64; jj += 8){
            u16x8 pk;
            #pragma unroll
            for (int e = 0; e < 8; ++e)
                pk[e] = vs[(size_t)(j0 + jj + e) * 2048];
            *(u16x8*)&KV[d][j0 + jj] = pk;
        }
    }

    __syncthreads();

    f32x4 oc[8];
    #pragma unroll
    for (int ni = 0; ni < 8; ++ni) oc[ni] = zero;
    #pragma unroll
    for (int kc = 0; kc < 4; ++kc){
        bf16x8 pf = *(const bf16x8*)&Pls[wid][llo][kc*32 + lhi*8];
        #pragma unroll
        for (int ni = 0; ni < 8; ++ni){
            bf16x8 vf = *(const bf16x8*)&KV[ni*16 + llo][kc*32 + lhi*8];
            oc[ni] = mfma16(pf, vf, oc[ni]);
        }
    }

    #pragma unroll
    for (int ni = 0; ni < 8; ++ni){
        #pragma unroll
        for (int r = 0; r < 4; ++r){
            const size_t row = (size_t)(qbase + lhi*4 + r);
            ao[row * 16384 + h*128 + ni*16 + llo] = f2bf(oc[ni][r]);
        }
    }
}

// ---------------- launch ----------------
extern "C" void kernel_launch(void* const* d_in, const int* in_sizes, int n_in,
                              void* d_out, int out_size, void* d_ws, size_t ws_size,
                              hipStream_t stream)
{
    const float* x  = (const float*)d_in[0];
    const float* Wq = (const float*)d_in[1];
    const float* bq = (const float*)d_in[2];
    const float* Wk = (const float*)d_in[3];
    const float* bk = (const float*)d_in[4];
    const float* Wv = (const float*)d_in[5];
    const float* bv = (const float*)d_in[6];
    const float* Wo = (const float*)d_in[7];
    const float* bo = (const float*)d_in[8];

    float* outp  = (float*)d_out;                       // (B,S,E)
    float* k_out = outp + (size_t)33554432;             // (B,S,HKV,D)
    float* v_out = outp + (size_t)41943040;             // (B,S,HKV,D)

    // ws layout (peak 352 MB): [xb 64M][kb2 16M][vb2 16M][qb 128M][Wt 128M]
    char* w = (char*)d_ws;
    unsigned short* xb  = (unsigned short*)(w);
    unsigned short* kb2 = (unsigned short*)(w + 67108864ull);
    unsigned short* vb2 = (unsigned short*)(w + 83886080ull);
    unsigned short* qb  = (unsigned short*)(w + 100663296ull);
    unsigned short* Wt  = (unsigned short*)(w + 234881024ull);

    cvt_x_kernel<<<32768, 256, 0, stream>>>(x, xb);

    // qkv GEMM in 5 column chunks of 4096 (grid 256 = exactly 1 block/CU round)
    for (int c = 0; c < 4; ++c){
        tr_kernel<<<dim3(128, 64), 256, 0, stream>>>(Wq, 16384, c*4096, 8192, Wt);
        gemm256_kernel<0><<<256, 512, 0, stream>>>(xb, 8192, Wt, c*4096, bq, bk, bv, nullptr,
                                                   qb, k_out, v_out, vb2, nullptr);
    }
    // chunk 4 = Wk (2048) + Wv (2048)
    tr_kernel<<<dim3(128, 32), 256, 0, stream>>>(Wk, 2048, 0, 8192, Wt);
    tr_kernel<<<dim3(128, 32), 256, 0, stream>>>(Wv, 2048, 0, 8192, Wt + (size_t)2048*8192);
    gemm256_kernel<0><<<256, 512, 0, stream>>>(xb, 8192, Wt, 16384, bq, bk, bv, nullptr,
                                               qb, k_out, v_out, vb2, nullptr);

    rope_q_kernel<<<131072, 256, 0, stream>>>(qb);
    rope_k_kernel<<<16384, 256, 0, stream>>>(k_out, kb2);
    attn_kernel<<<8192, 256, 0, stream>>>(qb, kb2, vb2, qb);   // ao in-place over q

    // out-proj in 2 column halves of 4096
    for (int hh = 0; hh < 2; ++hh){
        tr_kernel<<<dim3(256, 64), 256, 0, stream>>>(Wo, 8192, hh*4096, 16384, Wt);
        gemm256_kernel<1><<<256, 512, 0, stream>>>(qb, 16384, Wt, hh*4096, nullptr, nullptr, nullptr, bo,
                                                   nullptr, nullptr, nullptr, nullptr, outp);
    }
}